// Round 14
// baseline (209.187 us; speedup 1.0000x reference)
//
#include <hip/hip_runtime.h>
#include <math.h>

// Dims (fixed by the reference)
#define B_   2048
#define C_   64
#define H_   768
#define NC_  1000
#define H2_  384   // H/2
#define H4_  192   // H/4
#define RIN_ 960   // H + H/4

using short8 = __attribute__((ext_vector_type(8))) short;
using f32x4  = __attribute__((ext_vector_type(4))) float;

__device__ __forceinline__ float silu_(float x){
    float e = __expf(-x);
    return x * __fdividef(1.f, 1.f + e);
}
// round-to-nearest-even f32 -> bf16
__device__ __forceinline__ unsigned short f2bf_(float x){
    unsigned int u = __float_as_uint(x);
    u += 0x7fffu + ((u >> 16) & 1u);
    return (unsigned short)(u >> 16);
}
// truncating f32 -> bf16 (lo residuals; residual-of-residual < 2^-17)
__device__ __forceinline__ unsigned short f2bft_(float x){
    return (unsigned short)(__float_as_uint(x) >> 16);
}
__device__ __forceinline__ float bf2f_(unsigned short h){
    return __uint_as_float(((unsigned int)h) << 16);
}

__global__ void k_sentinel(float* __restrict__ out, float code){ out[0] = code; }

// ---------------------------------------------------------------------------
// K1: split w1 rows 0..767 -> chunk-major bf16 hi/lo (the only t1 dependency)
// ---------------------------------------------------------------------------
__global__ __launch_bounds__(256) void k_w1split(const float* __restrict__ w1,
                                                 unsigned short* __restrict__ w1hi,
                                                 unsigned short* __restrict__ w1lo)
{
    const int idx = blockIdx.x * 256 + threadIdx.x;
    const int k = idx / H2_, j = idx - k * H2_;
    float x = w1[idx];
    unsigned short h = f2bf_(x);
    size_t dst = (size_t)(k >> 5) * (H2_ * 32) + (size_t)j * 32 + (k & 31);
    w1hi[dst] = h;
    w1lo[dst] = f2bft_(x - bf2f_(h));
}

// ---------------------------------------------------------------------------
// K2 (combo): blockIdx dispatch over independent work
//   [0,256)     : T1 = te @ w1[:768] + b1 (MFMA bf16x3, 4 waves x 48 cols)
//   [256,544)   : split w2 (384x192) -> chunk-major bf16 hi/lo
//   [544,1544)  : E1[id] = emb[id] @ w1[768:960]
//   [1544]      : int64-vs-int32 detector on ids
// ---------------------------------------------------------------------------
#define CB_T1E_  256
#define CB_W2E_  544
#define CB_E1E_  1544
__global__ __launch_bounds__(256) void k_combo(const float* __restrict__ te,
                                               const float* __restrict__ w1,
                                               const float* __restrict__ w2,
                                               const float* __restrict__ emb,
                                               const int*   __restrict__ ids32,
                                               const unsigned short* __restrict__ w1hi,
                                               const unsigned short* __restrict__ w1lo,
                                               const float* __restrict__ b1,
                                               float* __restrict__ T1,
                                               unsigned short* __restrict__ w2hi,
                                               unsigned short* __restrict__ w2lo,
                                               float* __restrict__ E1,
                                               int* __restrict__ flag)
{
    __shared__ float er[H4_];
    __shared__ int any_nz;
    const int bb = blockIdx.x, t = threadIdx.x;

    if (bb < CB_T1E_) {
        // ---- T1 MFMA: block covers 16 task-rows x 192 cols
        const int bx = bb >> 1, by = bb & 1;
        const int b0 = bx * 16;
        const int jb = by * 192;
        const int w = t >> 6, l = t & 63;
        const int m = l & 15, g = l >> 4;
        const int row = b0 + m;

        f32x4 acc[3];
        #pragma unroll
        for (int jt = 0; jt < 3; ++jt) acc[jt] = (f32x4){0.f, 0.f, 0.f, 0.f};

        for (int ck = 0; ck < 24; ++ck) {
            const int kk = ck * 32;
            const float* pa = te + (size_t)row * H_ + kk + g * 8;
            float4 a0 = *(const float4*)pa;
            float4 a1 = *(const float4*)(pa + 4);
            float av[8] = {a0.x, a0.y, a0.z, a0.w, a1.x, a1.y, a1.z, a1.w};
            short8 ahi, alo;
            #pragma unroll
            for (int i = 0; i < 8; ++i) {
                unsigned short h = f2bf_(av[i]);
                ahi[i] = (short)h;
                alo[i] = (short)f2bft_(av[i] - bf2f_(h));
            }
            #pragma unroll
            for (int jt = 0; jt < 3; ++jt) {
                const int j = jb + w * 48 + jt * 16 + m;
                const size_t o = (size_t)ck * (H2_ * 32) + (size_t)j * 32 + g * 8;
                short8 bhi = *(const short8*)&w1hi[o];
                short8 blo = *(const short8*)&w1lo[o];
                acc[jt] = __builtin_amdgcn_mfma_f32_16x16x32_bf16(ahi, bhi, acc[jt], 0, 0, 0);
                acc[jt] = __builtin_amdgcn_mfma_f32_16x16x32_bf16(ahi, blo, acc[jt], 0, 0, 0);
                acc[jt] = __builtin_amdgcn_mfma_f32_16x16x32_bf16(alo, bhi, acc[jt], 0, 0, 0);
            }
        }
        #pragma unroll
        for (int jt = 0; jt < 3; ++jt) {
            const int j = jb + w * 48 + jt * 16 + m;
            const float bj = b1[j];
            #pragma unroll
            for (int reg = 0; reg < 4; ++reg)
                T1[(size_t)(b0 + g * 4 + reg) * H2_ + j] = acc[jt][reg] + bj;
        }
    } else if (bb < CB_W2E_) {
        const int idx = (bb - CB_T1E_) * 256 + t;      // < 384*192 exactly
        const int k = idx / H4_, j = idx - k * H4_;
        float x = w2[idx];
        unsigned short h = f2bf_(x);
        size_t dst = (size_t)(k >> 5) * (H4_ * 32) + (size_t)j * 32 + (k & 31);
        w2hi[dst] = h;
        w2lo[dst] = f2bft_(x - bf2f_(h));
    } else if (bb < CB_E1E_) {
        const int id = bb - CB_W2E_;
        if (t < H4_) er[t] = emb[id * H4_ + t];
        __syncthreads();
        for (int k = t; k < H2_; k += 256) {
            float acc = 0.f;
            const float* wc = w1 + (size_t)H_ * H2_ + k;
            #pragma unroll 8
            for (int r = 0; r < H4_; ++r) acc += er[r] * wc[(size_t)r * H2_];
            E1[id * H2_ + k] = acc;
        }
    } else {
        if (t == 0) any_nz = 0;
        __syncthreads();
        int local = 0;
        for (int i = t; i < 2048; i += 256)
            if (ids32[2 * i + 1] != 0) { local = 1; break; }
        if (local) atomicOr(&any_nz, 1);
        __syncthreads();
        if (t == 0) flag[0] = (any_nz == 0) ? 1 : 0;
    }
}

// ---------------------------------------------------------------------------
// K3: barrier-free MFMA main kernel, wave-per-row-tile decomposition.
// One block per task, 256 threads = 4 waves. Wave w owns rows [16w,16w+16),
// ALL 192 j-cols (12 j-tiles). Lane (m,g) computes ITS OWN A-fragment
// (row 16w+m, k-octet g) in-register: E1/T1 loads (reg-prefetched one chunk
// ahead) + silu + bf16 hi/lo split -> feeds 36 MFMAs/chunk. Zero LDS staging,
// zero main-loop barriers; 1x total stage VALU (R11's 4x duplication fixed
// by the rt<->wave swap). B-frags read by all 4 waves but 24KB/chunk fits L1.
// f64 tail; waves own disjoint c-rows -> single sredS write per c.
// LDS: 0.5 KB.
// ---------------------------------------------------------------------------
__global__ __launch_bounds__(256, 3) void k_main(const float* __restrict__ T1,
                                                 const float* __restrict__ E1,
                                                 const int*   __restrict__ ids,
                                                 const int*   __restrict__ labels,
                                                 const unsigned short* __restrict__ w2hi,
                                                 const unsigned short* __restrict__ w2lo,
                                                 const float* __restrict__ b2,
                                                 const float* __restrict__ w3,
                                                 const float* __restrict__ b3,
                                                 const float* __restrict__ cbias,
                                                 const int*   __restrict__ iflag,
                                                 float* __restrict__ out)
{
    __shared__ double sredS[C_];    // 512 B

    const int b = blockIdx.x;
    const int t = threadIdx.x;
    const int l = t & 63, w = t >> 6;        // lane, wave
    const int m = l & 15, g = l >> 4;        // frag row-in-tile / k-group

    const int i64 = iflag[0];
    const int row = 16 * w + m;              // this lane's contributor row
    const size_t roff = (size_t)b * C_ + row;
    const int id = i64 ? (int)((const long long*)ids)[roff] : ids[roff];

    const float* ep = E1 + (size_t)id * H2_;
    const float* tp = T1 + (size_t)b * H2_;

    f32x4 acc[12];
    #pragma unroll
    for (int jt = 0; jt < 12; ++jt) acc[jt] = (f32x4){0.f, 0.f, 0.f, 0.f};

    // prefetch chunk 0 A-inputs
    float4 e0 = *(const float4*)&ep[g * 8];
    float4 e1 = *(const float4*)&ep[g * 8 + 4];
    float4 t0 = *(const float4*)&tp[g * 8];
    float4 t1 = *(const float4*)&tp[g * 8 + 4];

    for (int ck = 0; ck < 12; ++ck) {
        // A-fragment from prefetched regs: silu + hi/lo split (bitwise same as R12)
        float xs[8] = {t0.x + e0.x, t0.y + e0.y, t0.z + e0.z, t0.w + e0.w,
                       t1.x + e1.x, t1.y + e1.y, t1.z + e1.z, t1.w + e1.w};
        short8 ahi, alo;
        #pragma unroll
        for (int i = 0; i < 8; ++i) {
            float x = silu_(xs[i]);
            unsigned short h = f2bf_(x);
            ahi[i] = (short)h;
            alo[i] = (short)f2bft_(x - bf2f_(h));
        }

        // prefetch next chunk's A-inputs (hides E1/T1 latency under MFMAs)
        if (ck + 1 < 12) {
            const int kn = (ck + 1) * 32 + g * 8;
            e0 = *(const float4*)&ep[kn];
            e1 = *(const float4*)&ep[kn + 4];
            t0 = *(const float4*)&tp[kn];
            t1 = *(const float4*)&tp[kn + 4];
        }

        // B-fragments (L1-resident: same 24KB stream for all waves/blocks) + MFMA
        const unsigned short* gbh = w2hi + (size_t)ck * (H4_ * 32) + g * 8;
        const unsigned short* gbl = w2lo + (size_t)ck * (H4_ * 32) + g * 8;
        #pragma unroll
        for (int jt = 0; jt < 12; ++jt) {
            const int j = jt * 16 + m;
            short8 bhi = *(const short8*)&gbh[(size_t)j * 32];
            short8 blo = *(const short8*)&gbl[(size_t)j * 32];
            acc[jt] = __builtin_amdgcn_mfma_f32_16x16x32_bf16(ahi, bhi, acc[jt], 0, 0, 0);
            acc[jt] = __builtin_amdgcn_mfma_f32_16x16x32_bf16(ahi, blo, acc[jt], 0, 0, 0);
            acc[jt] = __builtin_amdgcn_mfma_f32_16x16x32_bf16(alo, bhi, acc[jt], 0, 0, 0);
        }
    }

    // --- epilogue: h2 = silu(acc + b2); p[c] = sum_j h2 * w3  (f64)
    // lane holds D[c = 16w + g*4 + reg][j = jt*16 + m]
    double p[4] = {0.0, 0.0, 0.0, 0.0};
    #pragma unroll
    for (int jt = 0; jt < 12; ++jt) {
        const int j = jt * 16 + m;
        const float bj = b2[j];
        const double w3j = (double)w3[j];
        #pragma unroll
        for (int reg = 0; reg < 4; ++reg)
            p[reg] += (double)silu_(acc[jt][reg] + bj) * w3j;
    }
    #pragma unroll
    for (int reg = 0; reg < 4; ++reg) {
        double v = p[reg];
        v += __shfl_xor(v, 1);
        v += __shfl_xor(v, 2);
        v += __shfl_xor(v, 4);
        v += __shfl_xor(v, 8);
        p[reg] = v;
    }
    if (m == 0) {
        #pragma unroll
        for (int reg = 0; reg < 4; ++reg)
            sredS[16 * w + g * 4 + reg] = p[reg];
    }
    __syncthreads();

    if (t < C_) {
        const int c = t;
        const size_t off = (size_t)b * C_ + c;
        const int idc = i64 ? (int)((const long long*)ids)[off] : ids[off];
        const int lb  = i64 ? (int)((const long long*)labels)[off] : labels[off];

        double s = sredS[c];
        double est = 1.0 / (1.0 + exp(-(s + (double)b3[0])));
        double rel = 1.0 / (1.0 + exp(-(est + (double)cbias[idc])));
        out[B_ + (size_t)b * C_ + c] = (float)rel;

        // margin in f64; ties -> 0 (np argmax); (1-difficulty) factor dropped
        double mg = (lb == 1) ? rel : ((lb == 0) ? -rel : 0.0);
        #pragma unroll
        for (int o = 32; o > 0; o >>= 1) mg += __shfl_down(mg, o);
        if (t == 0) out[b] = (mg > 0.0) ? 1.0f : 0.0f;
    }
}

// ---------------------------------------------------------------------------
extern "C" void kernel_launch(void* const* d_in, const int* in_sizes, int n_in,
                              void* d_out, int out_size, void* d_ws, size_t ws_size,
                              hipStream_t stream)
{
    const float* te    = (const float*)d_in[0];
    const int*   ids   = (const int*)  d_in[1];
    const int*   labs  = (const int*)  d_in[2];
    const float* w1    = (const float*)d_in[3];
    const float* b1    = (const float*)d_in[4];
    const float* w2    = (const float*)d_in[5];
    const float* b2    = (const float*)d_in[6];
    const float* w3    = (const float*)d_in[7];
    const float* b3    = (const float*)d_in[8];
    const float* cbias = (const float*)d_in[14];
    const float* emb   = (const float*)d_in[13];
    float* out = (float*)d_out;

    const int expect[15] = {B_*H_, B_*C_, B_*C_, RIN_*H2_, H2_, H2_*H4_, H4_,
                            H4_, 1, H_*H2_, H2_, H2_, 1, NC_*H4_, NC_};
    if (n_in != 15) {
        k_sentinel<<<1, 1, 0, stream>>>(out, 3000.0f + (float)n_in);
        return;
    }
    for (int i = 0; i < 15; ++i) {
        if (in_sizes[i] != expect[i]) {
            k_sentinel<<<1, 1, 0, stream>>>(out, 2000.0f + 10.0f * (float)i);
            return;
        }
    }

    // ws layout: E1 f32 | T1 f32 | w1s hi/lo u16 | w2s hi/lo u16 | iflag
    const size_t nE1 = (size_t)NC_ * H2_;
    const size_t nT1 = (size_t)B_ * H2_;
    const size_t nW1 = (size_t)RIN_ * H2_;
    const size_t nW2 = (size_t)H2_ * H4_;
    const size_t need = nE1 * 4 + nT1 * 4 + nW1 * 2 * 2 + nW2 * 2 * 2 + 16;
    if (ws_size < need) {
        k_sentinel<<<1, 1, 0, stream>>>(out, 1000.0f + (float)((double)ws_size / (1024.0 * 1024.0)));
        return;
    }
    float* ws = (float*)d_ws;
    float* E1 = ws;
    float* T1 = E1 + nE1;
    unsigned short* w1hi = (unsigned short*)(T1 + nT1);
    unsigned short* w1lo = w1hi + nW1;
    unsigned short* w2hi = w1lo + nW1;
    unsigned short* w2lo = w2hi + nW2;
    int* iflag = (int*)(w2lo + nW2);

    k_w1split<<<1152, 256, 0, stream>>>(w1, w1hi, w1lo);
    k_combo<<<CB_E1E_ + 1, 256, 0, stream>>>(te, w1, w2, emb, ids,
                                             w1hi, w1lo, b1, T1,
                                             w2hi, w2lo, E1, iflag);
    k_main<<<B_, 256, 0, stream>>>(T1, E1, ids, labs, w2hi, w2lo, b2, w3, b3, cbias, iflag, out);
}